// Round 1
// 80.346 us; speedup vs baseline: 1.0218x; 1.0218x over previous
//
#include <hip/hip_runtime.h>

// x:      (8, 3, 512, 512) fp32
// shift:  (16, 3) fp32
// slopes: (16, 3) fp32
// conv_w: (3,)  fp32
// conv_b: (1,)  fp32
// out:    (8, 1, 512, 512) fp32
//
// out[b,h,w] = clip( conv_b + sum_c conv_w[c] * sum_p slopes[p,c]*relu(x[b,c,h,w]-shift[p,c]), 0, 1 )
//
// Identity used: sum_p m_p*relu(x-s_p) = (0.5*sum m)*x - 0.5*sum(m*s) + sum_p (0.5*m_p)*|x - s_p|
//   -> inner loop is 2 VALU ops/point (v_sub + v_fma with abs modifier) instead of 3.
// 8 elements (2 float4) per thread amortize the per-channel uniform coefficient prep.

typedef float f4v __attribute__((ext_vector_type(4)));

constexpr int NPTS = 16;
constexpr int C    = 3;
constexpr int HW4  = 65536;   // float4s per (b,c) plane = 512*512/4 = 2^16

__global__ __launch_bounds__(256)
void curve_channel_kernel(const f4v*  __restrict__ x,
                          const float* __restrict__ shift,   // (NPTS, C)
                          const float* __restrict__ slopes,  // (NPTS, C)
                          const float* __restrict__ conv_w,  // (C,)
                          const float* __restrict__ conv_b,  // (1,)
                          f4v*        __restrict__ out,
                          int n4)                             // total float4 outputs
{
    // Each block covers 512 consecutive float4s: threads [0,256) take i0, then i0+256.
    const int i0 = blockIdx.x * 512 + (int)threadIdx.x;
    if (i0 >= n4) return;
    const int  i1   = i0 + 256;
    const bool has1 = (i1 < n4);

    const int b0 = i0 >> 16, h0 = i0 & (HW4 - 1);
    const int b1 = i1 >> 16, h1 = i1 & (HW4 - 1);
    const f4v* xp0 = x + (size_t)b0 * (C * HW4) + h0;
    const f4v* xp1 = x + (size_t)b1 * (C * HW4) + h1;

    const float bias = conv_b[0];
    float acc[8];
#pragma unroll
    for (int e = 0; e < 8; ++e) acc[e] = bias;

#pragma unroll
    for (int c = 0; c < C; ++c) {
        const f4v v0 = xp0[(size_t)c * HW4];
        f4v v1 = (f4v){0.f, 0.f, 0.f, 0.f};
        if (has1) v1 = xp1[(size_t)c * HW4];
        const float xv[8] = { v0[0], v0[1], v0[2], v0[3],
                              v1[0], v1[1], v1[2], v1[3] };
        const float w = conv_w[c];

        // Wave-uniform coefficient prep (scalar loads; VALU fp, amortized over 8 elems).
        float sv[NPTS], hm[NPTS];
        float A = 0.f, B = 0.f;
#pragma unroll
        for (int p = 0; p < NPTS; ++p) {
            sv[p] = shift[p * C + c];          // s_p
            hm[p] = 0.5f * slopes[p * C + c];  // 0.5*m_p
            A += hm[p];                         // 0.5*sum(m)
            B  = fmaf(-hm[p], sv[p], B);        // -0.5*sum(m*s)
        }

        float y[8];
#pragma unroll
        for (int e = 0; e < 8; ++e) y[e] = fmaf(A, xv[e], B);

#pragma unroll
        for (int p = 0; p < NPTS; ++p) {
#pragma unroll
            for (int e = 0; e < 8; ++e)
                y[e] = fmaf(hm[p], fabsf(xv[e] - sv[p]), y[e]);  // v_sub + v_fma(|.|)
        }

#pragma unroll
        for (int e = 0; e < 8; ++e) acc[e] = fmaf(w, y[e], acc[e]);
    }

    f4v o0, o1;
#pragma unroll
    for (int e = 0; e < 4; ++e) o0[e] = fminf(fmaxf(acc[e],     0.f), 1.f);
#pragma unroll
    for (int e = 0; e < 4; ++e) o1[e] = fminf(fmaxf(acc[4 + e], 0.f), 1.f);

    __builtin_nontemporal_store(o0, &out[i0]);          // write-once output: don't pollute L2/L3
    if (has1) __builtin_nontemporal_store(o1, &out[i1]);
}

extern "C" void kernel_launch(void* const* d_in, const int* in_sizes, int n_in,
                              void* d_out, int out_size, void* d_ws, size_t ws_size,
                              hipStream_t stream)
{
    const float* x      = (const float*)d_in[0];
    const float* shift  = (const float*)d_in[1];
    const float* slopes = (const float*)d_in[2];
    const float* conv_w = (const float*)d_in[3];
    const float* conv_b = (const float*)d_in[4];

    const int n4     = out_size / 4;           // float4 outputs
    const int blocks = (n4 + 511) / 512;       // 512 float4s per block (2 per thread)

    curve_channel_kernel<<<dim3(blocks), dim3(256), 0, stream>>>(
        (const f4v*)x, shift, slopes, conv_w, conv_b, (f4v*)d_out, n4);
}